// Round 13
// baseline (12410.230 us; speedup 1.0000x reference)
//
#include <hip/hip_runtime.h>
#include <math.h>

// Problem constants (Elman RNN)
#define TT 4096
#define HH 2048
#define OO 512

#define NB  128    // scan blocks
#define RPB 16     // rows per block = HH/NB
#define MBW (HH/2) // mailbox words per buffer (fp16 x2 per word)

#define CHUNK_T 64             // t-rows per chunk
#define NCHUNK  (TT/CHUNK_T)   // 64 chunks
#define HTILE   128
#define NHT     (HH/HTILE)     // 16 h-tiles per chunk (phase 1)

typedef __fp16 half2v __attribute__((ext_vector_type(2)));

// ---------------------------------------------------------------------------
// R13 FUSED single dispatch, all three phases, NO scan-concurrent traffic:
//   blocks 0..127   : scan -- exact R10/R12 core (agent outs stores +
//                     scan_done release-add per 64 steps, post-publish).
//   blocks 128..255 : phase-1 xp GEMM, then SLEEP-POLL until the scan's
//                     final chunk retires (R12's mistake: phase-3 work
//                     overlapped the scan -> fabric pressure added
//                     ~0.65us/step = +2.7ms; 3rd confirmation of the
//                     "nothing shares the fabric with the live exchange"
//                     rule).
//   TAIL (all 256 blocks): after scan_done[63]==128, each block computes
//   ONE 64x128 out-tile (256 tasks = 64 chunks x 4 o-tiles). Replaces the
//   trailing GEMM dispatch (345us incl. launch) with ~150us in-kernel.
// ---------------------------------------------------------------------------
__global__ __launch_bounds__(1024) void rnn_fused(
    const float* __restrict__ x,     // (T,H) input
    const float* __restrict__ Wih,   // (H,H)
    const float* __restrict__ bih,   // (H)
    const float* __restrict__ Whh,   // (H,H)
    const float* __restrict__ bhh,   // (H)
    const float* __restrict__ h0,    // (H)
    const float* __restrict__ Wlin,  // (O,H)
    const float* __restrict__ blin,  // (O)
    float* __restrict__ xp,          // (T,H) ws: input projection
    float* __restrict__ outs,        // (T,H) ws: hidden states
    float* __restrict__ out,         // (T,O) final output
    unsigned long long* __restrict__ mbox,  // [2][MBW] tagged fp16x2 mailbox
    int* __restrict__ chunk_done,    // [NCHUNK] xp-chunk arm counters
    int* __restrict__ scan_done)     // [NCHUNK] scan-chunk retire counters
{
    const int tid = threadIdx.x;     // 0..1023

    // shared allocations (union across phases; ~25 KB total)
    __shared__ float As[16][65];     // [kk][row], padded
    __shared__ float Bs[16][132];    // [kk][col], padded+aligned
    __shared__ float hs[HH];         // staged h (fp32), wave-private
    __shared__ float partial[16][68];// [k-chunk wave][q*17 + r]

    // GEMM thread mapping (phases 1 & 3)
    const int ty   = tid >> 5;          // 0..31 -> rows ty*2, ty*2+1
    const int tx   = tid & 31;          // 0..31 -> cols tx*4..
    const int arow = tid >> 4;          // 0..63
    const int akk  = tid & 15;
    const int bcol = tid >> 3;          // 0..127
    const int bkk  = (tid & 7) * 2;

    if (blockIdx.x >= NB) {
        // ----------------- worker: phase 1 (unchanged R10/R12) -----------------
        const int w2 = blockIdx.x - NB;   // 0..127

        for (int round = 0; round < (NCHUNK * NHT) / 128; ++round) {
            const int tile  = w2 + 128 * round;   // t-major: early t first
            const int chunk = tile >> 4;
            const int htile = tile & 15;
            const int bm = chunk * CHUNK_T;
            const int bn = htile * HTILE;

            float acc[2][4];
#pragma unroll
            for (int i = 0; i < 2; ++i)
#pragma unroll
                for (int j = 0; j < 4; ++j) acc[i][j] = 0.f;

            for (int k0 = 0; k0 < HH; k0 += 16) {
                float  av = x[(size_t)(bm + arow) * HH + k0 + akk];
                float2 bv = *(const float2*)&Wih[(size_t)(bn + bcol) * HH + k0 + bkk];
                __syncthreads();
                As[akk][arow]     = av;
                Bs[bkk][bcol]     = bv.x;
                Bs[bkk + 1][bcol] = bv.y;
                __syncthreads();
#pragma unroll
                for (int kk = 0; kk < 16; ++kk) {
                    float a0 = As[kk][ty * 2];
                    float a1 = As[kk][ty * 2 + 1];
                    float b0 = Bs[kk][tx * 4 + 0];
                    float b1 = Bs[kk][tx * 4 + 1];
                    float b2 = Bs[kk][tx * 4 + 2];
                    float b3 = Bs[kk][tx * 4 + 3];
                    acc[0][0] += a0 * b0; acc[0][1] += a0 * b1;
                    acc[0][2] += a0 * b2; acc[0][3] += a0 * b3;
                    acc[1][0] += a1 * b0; acc[1][1] += a1 * b1;
                    acc[1][2] += a1 * b2; acc[1][3] += a1 * b3;
                }
            }
#pragma unroll
            for (int i = 0; i < 2; ++i) {
                const int m = bm + ty * 2 + i;
#pragma unroll
                for (int j = 0; j < 4; ++j) {
                    const int n = bn + tx * 4 + j;
                    __hip_atomic_store(&xp[(size_t)m * HH + n],
                                       acc[i][j] + bih[n],
                                       __ATOMIC_RELAXED, __HIP_MEMORY_SCOPE_AGENT);
                }
            }
            __syncthreads();
            if (tid == 0)
                __hip_atomic_fetch_add(&chunk_done[chunk], 1,
                                       __ATOMIC_RELEASE, __HIP_MEMORY_SCOPE_AGENT);
        }
        // fall through to tail gate (sleep-poll until scan fully retired)
    } else {
        // ------------------------- scan (exact R10 core) -----------------------
        const int b    = blockIdx.x;     // 0..127
        const int wave = tid >> 6;       // 0..15
        const int lane = tid & 63;
        const int r    = lane & 15;      // local row 0..15
        const int q    = lane >> 4;      // 0..3: interleaved 4-float subchunk
        const int row  = b * RPB + r;    // global row this thread accumulates
        const int m0   = wave * 64 + lane;      // my mailbox word (2 rows)
        const int s0   = wave * 128 + 2 * lane; // my 2 floats in hs

        // weights pinned (atomic loads can't be rematerialized into the loop)
        float w[32];
#pragma unroll
        for (int jj = 0; jj < 8; ++jj)
#pragma unroll
            for (int i = 0; i < 4; ++i)
                w[jj * 4 + i] = __hip_atomic_load(
                    &Whh[(size_t)row * HH + wave * 128 + jj * 16 + q * 4 + i],
                    __ATOMIC_RELAXED, __HIP_MEMORY_SCOPE_WORKGROUP);

        const bool is_writer = (wave == 0) && (lane < RPB);
        const float bias = is_writer ? bhh[b * RPB + lane] : 0.f;

        int last_c = -1;

        for (int t = 0; t < TT; ++t) {
            // xp gating + load: writer lanes only; poll only at chunk boundary
            float xpv = 0.f;
            if (is_writer) {
                const int c = t >> 6;   // t / CHUNK_T
                if (c != last_c) {
                    while (__hip_atomic_load(&chunk_done[c],
                            __ATOMIC_RELAXED, __HIP_MEMORY_SCOPE_AGENT) < NHT) {}
                    last_c = c;
                }
                xpv = __hip_atomic_load(&xp[(size_t)t * HH + b * RPB + lane],
                                        __ATOMIC_RELAXED, __HIP_MEMORY_SCOPE_AGENT);
            }

            // stage MY wave's 128-float chunk: ONE tagged word per lane
            if (t == 0) {
                float2 hv; hv.x = h0[s0]; hv.y = h0[s0 + 1];
                *(float2*)&hs[s0] = hv;
            } else {
                const unsigned int want = (unsigned int)t;
                const unsigned long long* mb = mbox + (size_t)(t & 1) * MBW;
                unsigned long long v;
                do {
                    v = __hip_atomic_load(&mb[m0],
                        __ATOMIC_RELAXED, __HIP_MEMORY_SCOPE_AGENT);
                } while ((unsigned int)(v >> 32) != want);
                half2v hp = __builtin_bit_cast(half2v, (unsigned int)v);
                float2 hv;
                hv.x = (float)hp[0];
                hv.y = (float)hp[1];
                *(float2*)&hs[s0] = hv;   // same-wave write->read: lgkmcnt only
            }

            // matvec partial: 8 broadcast ds_read_b128 + 32 FMA
            const float* hk = &hs[wave * 128 + q * 4];
            float p = 0.f;
#pragma unroll
            for (int jj = 0; jj < 8; ++jj) {
                float4 h4 = *(const float4*)&hk[jj * 16];
                p += w[jj * 4 + 0] * h4.x + w[jj * 4 + 1] * h4.y
                   + w[jj * 4 + 2] * h4.z + w[jj * 4 + 3] * h4.w;
            }
            partial[wave][q * 17 + r] = p;
            __syncthreads();   // (B) the ONLY barrier per step

            if (wave == 0) {
                const int idx = (lane >> 4) * 17 + (lane & 15);
                float s = 0.f;
#pragma unroll
                for (int g = 0; g < 16; ++g) s += partial[g][idx];
                s += __shfl_xor(s, 16, 64);   // fold qq bit 0
                s += __shfl_xor(s, 32, 64);   // fold qq bit 1
                float z = xpv + bias + s;
                z = fminf(15.f, fmaxf(-15.f, z));
                float e = __builtin_exp2f(z * 2.885390082f);
                float hv = (e - 1.f) * __builtin_amdgcn_rcpf(e + 1.f);
                // pack rows 2i,2i+1 into lane i (i<8): 64B-line publish FIRST
                float ha = __shfl(hv, 2 * lane, 64);
                float hb = __shfl(hv, 2 * lane + 1, 64);
                if (lane < 8) {
                    half2v pk2 = __builtin_amdgcn_cvt_pkrtz(ha, hb);
                    unsigned int pb = __builtin_bit_cast(unsigned int, pk2);
                    unsigned long long word =
                        ((unsigned long long)(unsigned int)(t + 1) << 32) |
                        (unsigned long long)pb;
                    __hip_atomic_store(&mbox[(size_t)((t + 1) & 1) * MBW + b * 8 + lane],
                                       word, __ATOMIC_RELAXED, __HIP_MEMORY_SCOPE_AGENT);
                }
                // outs store + chunk retire: post-publish, off critical path
                if (lane < RPB)
                    __hip_atomic_store(&outs[(size_t)t * HH + b * RPB + lane], hv,
                                       __ATOMIC_RELAXED, __HIP_MEMORY_SCOPE_AGENT);
                if ((lane == 0) && ((t & 63) == 63))
                    __hip_atomic_fetch_add(&scan_done[t >> 6], 1,
                                           __ATOMIC_RELEASE, __HIP_MEMORY_SCOPE_AGENT);
            }
        }
        // fall through to tail
    }

    // ---------------- TAIL: phase 3, ALL 256 blocks, post-scan ----------------
    // gate on the FINAL chunk: no phase-3 traffic can overlap the scan
    if (tid == 0) {
        while (__hip_atomic_load(&scan_done[NCHUNK - 1],
                __ATOMIC_ACQUIRE, __HIP_MEMORY_SCOPE_AGENT) < NB)
            __builtin_amdgcn_s_sleep(32);
    }
    __syncthreads();

    {
        const int task = blockIdx.x;          // 0..255 (= 64 chunks x 4 o-tiles)
        const int bm   = (task >> 2) * CHUNK_T;
        const int bn   = (task & 3) * HTILE;

        float acc[2][4];
#pragma unroll
        for (int i = 0; i < 2; ++i)
#pragma unroll
            for (int j = 0; j < 4; ++j) acc[i][j] = 0.f;

        for (int k0 = 0; k0 < HH; k0 += 16) {
            // A = outs rows: agent loads (bypass possibly-stale L2 poison)
            float av = __hip_atomic_load(
                &outs[(size_t)(bm + arow) * HH + k0 + akk],
                __ATOMIC_RELAXED, __HIP_MEMORY_SCOPE_AGENT);
            float2 bv = *(const float2*)&Wlin[(size_t)(bn + bcol) * HH + k0 + bkk];
            __syncthreads();
            As[akk][arow]     = av;
            Bs[bkk][bcol]     = bv.x;
            Bs[bkk + 1][bcol] = bv.y;
            __syncthreads();
#pragma unroll
            for (int kk = 0; kk < 16; ++kk) {
                float a0 = As[kk][ty * 2];
                float a1 = As[kk][ty * 2 + 1];
                float b0 = Bs[kk][tx * 4 + 0];
                float b1 = Bs[kk][tx * 4 + 1];
                float b2 = Bs[kk][tx * 4 + 2];
                float b3 = Bs[kk][tx * 4 + 3];
                acc[0][0] += a0 * b0; acc[0][1] += a0 * b1;
                acc[0][2] += a0 * b2; acc[0][3] += a0 * b3;
                acc[1][0] += a1 * b0; acc[1][1] += a1 * b1;
                acc[1][2] += a1 * b2; acc[1][3] += a1 * b3;
            }
        }
#pragma unroll
        for (int i = 0; i < 2; ++i) {
            const int m = bm + ty * 2 + i;
#pragma unroll
            for (int j = 0; j < 4; ++j) {
                const int n = bn + tx * 4 + j;
                out[(size_t)m * OO + n] = acc[i][j] + blin[n];
            }
        }
    }
}

// ---------------------------------------------------------------------------
extern "C" void kernel_launch(void* const* d_in, const int* in_sizes, int n_in,
                              void* d_out, int out_size, void* d_ws, size_t ws_size,
                              hipStream_t stream)
{
    const float* x     = (const float*)d_in[0];  // (T,1,H)
    const float* W_ih  = (const float*)d_in[1];  // (H,H)
    const float* W_hh  = (const float*)d_in[2];  // (H,H)
    const float* b_ih  = (const float*)d_in[3];  // (H)
    const float* b_hh  = (const float*)d_in[4];  // (H)
    const float* W_lin = (const float*)d_in[5];  // (O,H)
    const float* b_lin = (const float*)d_in[6];  // (O)
    const float* h0    = (const float*)d_in[7];  // (1,1,H)
    float* out = (float*)d_out;                  // (T,1,O)

    char* ws = (char*)d_ws;
    float* xp    = (float*)ws;                                       // 32 MB
    float* outs  = (float*)(ws + (size_t)TT * HH * 4);               // 32 MB
    unsigned long long* mbox =
        (unsigned long long*)(ws + 2 * (size_t)TT * HH * 4);         // 16 KB
    int* chunk_done =
        (int*)(ws + 2 * (size_t)TT * HH * 4 + 2 * MBW * 8);          // 256 B
    int* scan_done = chunk_done + NCHUNK;                            // 256 B

    // counters must start at 0 (ws arrives poisoned: 0xAAAAAAAA is negative
    // as int -> polls would spin forever). One memset covers both arrays.
    // mailbox needs no init (t==0 reads h0; poisoned tag never matches).
    hipMemsetAsync(chunk_done, 0, 2 * NCHUNK * sizeof(int), stream);

    // single dispatch: phase 1 (workers) + scan + phase 3 (all blocks, tail)
    rnn_fused<<<2 * NB, 1024, 0, stream>>>(
        x, W_ih, b_ih, W_hh, b_hh, h0, W_lin, b_lin,
        xp, outs, out, mbox, chunk_done, scan_done);
}

// Round 14
// 7425.410 us; speedup vs baseline: 1.6713x; 1.6713x over previous
//
#include <hip/hip_runtime.h>
#include <math.h>

// Problem constants (Elman RNN)
#define TT 4096
#define HH 2048
#define OO 512

#define NB  128    // scan blocks
#define RPB 16     // rows per block = HH/NB
#define MBW (HH/2) // mailbox words per buffer (fp16 x2 per word)

#define CHUNK_T 64             // t-rows per xp chunk
#define NCHUNK  (TT/CHUNK_T)   // 64 chunks
#define HTILE   128
#define NHT     (HH/HTILE)     // 16 h-tiles per chunk

typedef __fp16 half2v __attribute__((ext_vector_type(2)));

// ---------------------------------------------------------------------------
// Trailing phase 3: fp32 NT GEMM  C[m,n] = sum_k A[m,k]*B[n,k] + bias[n]
// R14: 128x64 tiles -> grid 32x8 = 256 blocks (R10 used 128x128 -> only 128
// blocks = half the machine at 26 TF). 256 threads, 8x4 acc/thread, BK=8.
// ---------------------------------------------------------------------------
__global__ __launch_bounds__(256) void gemm_nt_bias64(
    const float* __restrict__ A, const float* __restrict__ B,
    const float* __restrict__ bias, float* __restrict__ C,
    int M, int N, int K)
{
    __shared__ float As[8][128];
    __shared__ float Bs[8][72];      // 64 + pad

    const int tid = threadIdx.x;
    const int bm = blockIdx.x * 128;
    const int bn = blockIdx.y * 64;

    // staging: A = 1024 floats (float4/thread), B = 512 floats (float2/thread)
    const int lrow = tid >> 1;          // 0..127
    const int lk   = (tid & 1) * 4;     // 0 or 4
    const int brow = tid >> 2;          // 0..63
    const int bkk  = (tid & 3) * 2;     // 0,2,4,6

    const int ty = tid >> 4;            // 0..15
    const int tx = tid & 15;            // 0..15

    float acc[8][4];
#pragma unroll
    for (int i = 0; i < 8; i++)
#pragma unroll
        for (int j = 0; j < 4; j++) acc[i][j] = 0.f;

    for (int k0 = 0; k0 < K; k0 += 8) {
        float4 av = *(const float4*)&A[(size_t)(bm + lrow) * K + k0 + lk];
        float2 bv = *(const float2*)&B[(size_t)(bn + brow) * K + k0 + bkk];
        __syncthreads();
        As[lk + 0][lrow] = av.x; As[lk + 1][lrow] = av.y;
        As[lk + 2][lrow] = av.z; As[lk + 3][lrow] = av.w;
        Bs[bkk][brow]     = bv.x;
        Bs[bkk + 1][brow] = bv.y;
        __syncthreads();
#pragma unroll
        for (int kk = 0; kk < 8; kk++) {
            float a[8], b[4];
            *(float4*)&a[0] = *(const float4*)&As[kk][ty * 4];
            *(float4*)&a[4] = *(const float4*)&As[kk][64 + ty * 4];
            *(float4*)&b[0] = *(const float4*)&Bs[kk][tx * 4];
#pragma unroll
            for (int i = 0; i < 8; i++)
#pragma unroll
                for (int j = 0; j < 4; j++)
                    acc[i][j] += a[i] * b[j];
        }
    }

    {
        const int n = bn + tx * 4;
        float4 bv = *(const float4*)&bias[n];
#pragma unroll
        for (int i = 0; i < 8; i++) {
            const int m = bm + ((i < 4) ? (ty * 4 + i) : (64 + ty * 4 + (i - 4)));
            float4 cv;
            cv.x = acc[i][0] + bv.x;
            cv.y = acc[i][1] + bv.y;
            cv.z = acc[i][2] + bv.z;
            cv.w = acc[i][3] + bv.w;
            *(float4*)&C[(size_t)m * N + n] = cv;
        }
    }
}

// ---------------------------------------------------------------------------
// R14 fused kernel: EXACT R10 structure (the validated best).
//   blocks 0..127   : scan (R10 core, plain cached outs stores)
//   blocks 128..255 : phase-1 xp GEMM workers, then EXIT (return).
// R12/R13 proved (4th confirmation of the fabric rule): ANY resident block
// during the scan -- even one s_sleep-paced acquire-polling thread --
// poisons the exchange (acquire@agent = per-XCD L2 invalidate each poll;
// R13: poll-only workers cost +5.3ms). Workers must be DEAD, not idle.
// ---------------------------------------------------------------------------
__global__ __launch_bounds__(1024) void rnn_fused(
    const float* __restrict__ x,     // (T,H) input
    const float* __restrict__ Wih,   // (H,H)
    const float* __restrict__ bih,   // (H)
    const float* __restrict__ Whh,   // (H,H)
    const float* __restrict__ bhh,   // (H)
    const float* __restrict__ h0,    // (H)
    float* __restrict__ xp,          // (T,H) ws: input projection
    float* __restrict__ outs,        // (T,H) ws: hidden states
    unsigned long long* __restrict__ mbox,  // [2][MBW] tagged fp16x2 mailbox
    int* __restrict__ chunk_done)    // [NCHUNK] xp-chunk arm counters
{
    const int tid = threadIdx.x;     // 0..1023

    if (blockIdx.x >= NB) {
        // ------------------- xp GEMM worker (exact R10) -------------------
        __shared__ float As[16][65];     // [kk][t-row], padded
        __shared__ float Bs[16][132];    // [kk][h-col], padded+aligned

        const int w2   = blockIdx.x - NB;   // 0..127
        const int ty   = tid >> 5;          // 0..31 -> t-rows ty*2, ty*2+1
        const int tx   = tid & 31;          // 0..31 -> h-cols tx*4..
        const int arow = tid >> 4;          // 0..63
        const int akk  = tid & 15;
        const int bcol = tid >> 3;          // 0..127
        const int bkk  = (tid & 7) * 2;

        for (int round = 0; round < (NCHUNK * NHT) / 128; ++round) {
            const int tile  = w2 + 128 * round;   // t-major: early t first
            const int chunk = tile >> 4;
            const int htile = tile & 15;
            const int bm = chunk * CHUNK_T;
            const int bn = htile * HTILE;

            float acc[2][4];
#pragma unroll
            for (int i = 0; i < 2; ++i)
#pragma unroll
                for (int j = 0; j < 4; ++j) acc[i][j] = 0.f;

            for (int k0 = 0; k0 < HH; k0 += 16) {
                float  av = x[(size_t)(bm + arow) * HH + k0 + akk];
                float2 bv = *(const float2*)&Wih[(size_t)(bn + bcol) * HH + k0 + bkk];
                __syncthreads();
                As[akk][arow]     = av;
                Bs[bkk][bcol]     = bv.x;
                Bs[bkk + 1][bcol] = bv.y;
                __syncthreads();
#pragma unroll
                for (int kk = 0; kk < 16; ++kk) {
                    float a0 = As[kk][ty * 2];
                    float a1 = As[kk][ty * 2 + 1];
                    float b0 = Bs[kk][tx * 4 + 0];
                    float b1 = Bs[kk][tx * 4 + 1];
                    float b2 = Bs[kk][tx * 4 + 2];
                    float b3 = Bs[kk][tx * 4 + 3];
                    acc[0][0] += a0 * b0; acc[0][1] += a0 * b1;
                    acc[0][2] += a0 * b2; acc[0][3] += a0 * b3;
                    acc[1][0] += a1 * b0; acc[1][1] += a1 * b1;
                    acc[1][2] += a1 * b2; acc[1][3] += a1 * b3;
                }
            }
#pragma unroll
            for (int i = 0; i < 2; ++i) {
                const int m = bm + ty * 2 + i;
#pragma unroll
                for (int j = 0; j < 4; ++j) {
                    const int n = bn + tx * 4 + j;
                    __hip_atomic_store(&xp[(size_t)m * HH + n],
                                       acc[i][j] + bih[n],
                                       __ATOMIC_RELAXED, __HIP_MEMORY_SCOPE_AGENT);
                }
            }
            __syncthreads();   // all waves' stores retired first
            if (tid == 0)
                __hip_atomic_fetch_add(&chunk_done[chunk], 1,
                                       __ATOMIC_RELEASE, __HIP_MEMORY_SCOPE_AGENT);
        }
        return;   // workers DIE here -- CUs go fully idle for the scan
    }

    // ------------------------- scan (exact R10 core) -----------------------
    const int b    = blockIdx.x;     // 0..127
    const int wave = tid >> 6;       // 0..15
    const int lane = tid & 63;
    const int r    = lane & 15;      // local row 0..15
    const int q    = lane >> 4;      // 0..3: interleaved 4-float subchunk
    const int row  = b * RPB + r;    // global row this thread accumulates
    const int m0   = wave * 64 + lane;      // my mailbox word (covers 2 rows)
    const int s0   = wave * 128 + 2 * lane; // my 2 floats in hs

    // weights pinned (atomic loads can't be rematerialized into the loop)
    float w[32];
#pragma unroll
    for (int jj = 0; jj < 8; ++jj)
#pragma unroll
        for (int i = 0; i < 4; ++i)
            w[jj * 4 + i] = __hip_atomic_load(
                &Whh[(size_t)row * HH + wave * 128 + jj * 16 + q * 4 + i],
                __ATOMIC_RELAXED, __HIP_MEMORY_SCOPE_WORKGROUP);

    const bool is_writer = (wave == 0) && (lane < RPB);
    const float bias = is_writer ? bhh[b * RPB + lane] : 0.f;

    __shared__ float hs[HH];               // staged h (fp32), wave-private
    __shared__ float partial[16][68];      // [k-chunk wave][q*17 + r]

    int last_c = -1;

    for (int t = 0; t < TT; ++t) {
        // xp gating + load: only writer lanes; poll only at chunk boundary
        float xpv = 0.f;
        if (is_writer) {
            const int c = t >> 6;   // t / CHUNK_T
            if (c != last_c) {
                while (__hip_atomic_load(&chunk_done[c],
                        __ATOMIC_RELAXED, __HIP_MEMORY_SCOPE_AGENT) < NHT) {}
                last_c = c;
            }
            xpv = __hip_atomic_load(&xp[(size_t)t * HH + b * RPB + lane],
                                    __ATOMIC_RELAXED, __HIP_MEMORY_SCOPE_AGENT);
        }

        // stage MY wave's 128-float chunk: ONE tagged word per lane
        if (t == 0) {
            float2 hv; hv.x = h0[s0]; hv.y = h0[s0 + 1];
            *(float2*)&hs[s0] = hv;
        } else {
            const unsigned int want = (unsigned int)t;
            const unsigned long long* mb = mbox + (size_t)(t & 1) * MBW;
            unsigned long long v;
            do {
                v = __hip_atomic_load(&mb[m0],
                    __ATOMIC_RELAXED, __HIP_MEMORY_SCOPE_AGENT);
            } while ((unsigned int)(v >> 32) != want);
            half2v hp = __builtin_bit_cast(half2v, (unsigned int)v);
            float2 hv;
            hv.x = (float)hp[0];
            hv.y = (float)hp[1];
            *(float2*)&hs[s0] = hv;   // same-wave write->read: lgkmcnt only
        }

        // matvec partial: 8 broadcast ds_read_b128 + 32 FMA (interleaved map)
        const float* hk = &hs[wave * 128 + q * 4];
        float p = 0.f;
#pragma unroll
        for (int jj = 0; jj < 8; ++jj) {
            float4 h4 = *(const float4*)&hk[jj * 16];
            p += w[jj * 4 + 0] * h4.x + w[jj * 4 + 1] * h4.y
               + w[jj * 4 + 2] * h4.z + w[jj * 4 + 3] * h4.w;
        }
        partial[wave][q * 17 + r] = p;
        __syncthreads();   // (B) the ONLY barrier per step

        if (wave == 0) {
            // lane l: row = l&15, qq = l>>4; sum over the 16 k-chunk waves
            const int idx = (lane >> 4) * 17 + (lane & 15);
            float s = 0.f;
#pragma unroll
            for (int g = 0; g < 16; ++g) s += partial[g][idx];
            s += __shfl_xor(s, 16, 64);   // fold qq bit 0
            s += __shfl_xor(s, 32, 64);   // fold qq bit 1
            float z = xpv + bias + s;
            z = fminf(15.f, fmaxf(-15.f, z));
            float e = __builtin_exp2f(z * 2.885390082f);
            float hv = (e - 1.f) * __builtin_amdgcn_rcpf(e + 1.f);
            // pack rows 2i,2i+1 into lane i (i<8): one 64B-line publish FIRST
            float ha = __shfl(hv, 2 * lane, 64);
            float hb = __shfl(hv, 2 * lane + 1, 64);
            if (lane < 8) {
                half2v pk2 = __builtin_amdgcn_cvt_pkrtz(ha, hb);
                unsigned int pb = __builtin_bit_cast(unsigned int, pk2);
                unsigned long long word =
                    ((unsigned long long)(unsigned int)(t + 1) << 32) |
                    (unsigned long long)pb;
                __hip_atomic_store(&mbox[(size_t)((t + 1) & 1) * MBW + b * 8 + lane],
                                   word, __ATOMIC_RELAXED, __HIP_MEMORY_SCOPE_AGENT);
            }
            if (lane < RPB)
                outs[(size_t)t * HH + b * RPB + lane] = hv;  // plain cached
        }
        // partial[w] overwrite for t+1 gated by wave w's next poll, which
        // requires this block's wave-0 publish (after the reads above).
    }
}

// ---------------------------------------------------------------------------
extern "C" void kernel_launch(void* const* d_in, const int* in_sizes, int n_in,
                              void* d_out, int out_size, void* d_ws, size_t ws_size,
                              hipStream_t stream)
{
    const float* x     = (const float*)d_in[0];  // (T,1,H)
    const float* W_ih  = (const float*)d_in[1];  // (H,H)
    const float* W_hh  = (const float*)d_in[2];  // (H,H)
    const float* b_ih  = (const float*)d_in[3];  // (H)
    const float* b_hh  = (const float*)d_in[4];  // (H)
    const float* W_lin = (const float*)d_in[5];  // (O,H)
    const float* b_lin = (const float*)d_in[6];  // (O)
    const float* h0    = (const float*)d_in[7];  // (1,1,H)
    float* out = (float*)d_out;                  // (T,1,O)

    char* ws = (char*)d_ws;
    float* xp    = (float*)ws;                                       // 32 MB
    float* outs  = (float*)(ws + (size_t)TT * HH * 4);               // 32 MB
    unsigned long long* mbox =
        (unsigned long long*)(ws + 2 * (size_t)TT * HH * 4);         // 16 KB
    int* chunk_done =
        (int*)(ws + 2 * (size_t)TT * HH * 4 + 2 * MBW * 8);          // 256 B

    // chunk counters must start at 0 (ws arrives poisoned); mailbox needs
    // no init (t==0 reads h0; poisoned tag never equals a wanted tag).
    hipMemsetAsync(chunk_done, 0, NCHUNK * sizeof(int), stream);

    // Fused phase 1 + phase 2: scan blocks 0..127, xp workers 128..255
    rnn_fused<<<2 * NB, 1024, 0, stream>>>(
        x, W_ih, b_ih, W_hh, b_hh, h0, xp, outs, mbox, chunk_done);

    // Phase 3: out = outs @ W_lin^T + b_lin (256 blocks, full machine)
    gemm_nt_bias64<<<dim3(TT / 128, OO / 64), 256, 0, stream>>>(
        outs, W_lin, b_lin, out, TT, OO, HH);
}

// Round 15
// 7359.965 us; speedup vs baseline: 1.6862x; 1.0089x over previous
//
#include <hip/hip_runtime.h>
#include <math.h>

// Problem constants (Elman RNN)
#define TT 4096
#define HH 2048
#define OO 512

#define NB  128    // scan blocks
#define RPB 16     // rows per block = HH/NB
#define MBW (HH/2) // mailbox words per buffer (fp16 x2 per word)

#define CHUNK_T 64             // t-rows per xp chunk
#define NCHUNK  (TT/CHUNK_T)   // 64 chunks
#define HTILE   128
#define NHT     (HH/HTILE)     // 16 h-tiles per chunk

typedef __fp16 half2v __attribute__((ext_vector_type(2)));

// ---------------------------------------------------------------------------
// Trailing phase 3: fp32 NT GEMM  C[m,n] = sum_k A[m,k]*B[n,k] + bias[n]
// R15: 64x64 tiles -> grid 64x8 = 512 blocks = 2 blocks/CU = 2 waves/SIMD
// (R14's 128x64 at 256 blocks had 1 wave/SIMD: no overlap to hide LDS
// latency + 2 barriers x 256 k-iters -> only 34 TF). 256 threads, 4x4
// acc/thread, BK=8, float2 staging (bank-free), float4 broadcast reads.
// ---------------------------------------------------------------------------
__global__ __launch_bounds__(256) void gemm_nt_bias64(
    const float* __restrict__ A, const float* __restrict__ B,
    const float* __restrict__ bias, float* __restrict__ C,
    int M, int N, int K)
{
    __shared__ float As[8][72];
    __shared__ float Bs[8][72];

    const int tid = threadIdx.x;
    const int bm = blockIdx.x * 64;
    const int bn = blockIdx.y * 64;

    // staging: 64 rows x 8 k = 512 floats each => float2 per thread
    const int srow = tid >> 2;          // 0..63
    const int skk  = (tid & 3) * 2;     // 0,2,4,6

    const int ty = tid >> 4;            // 0..15 -> rows ty*4..ty*4+3
    const int tx = tid & 15;            // 0..15 -> cols tx*4..tx*4+3

    float acc[4][4];
#pragma unroll
    for (int i = 0; i < 4; i++)
#pragma unroll
        for (int j = 0; j < 4; j++) acc[i][j] = 0.f;

    for (int k0 = 0; k0 < K; k0 += 8) {
        float2 av = *(const float2*)&A[(size_t)(bm + srow) * K + k0 + skk];
        float2 bv = *(const float2*)&B[(size_t)(bn + srow) * K + k0 + skk];
        __syncthreads();
        As[skk][srow]     = av.x;
        As[skk + 1][srow] = av.y;
        Bs[skk][srow]     = bv.x;
        Bs[skk + 1][srow] = bv.y;
        __syncthreads();
#pragma unroll
        for (int kk = 0; kk < 8; kk++) {
            float4 a4 = *(const float4*)&As[kk][ty * 4];
            float4 b4 = *(const float4*)&Bs[kk][tx * 4];
            float a[4] = {a4.x, a4.y, a4.z, a4.w};
            float b[4] = {b4.x, b4.y, b4.z, b4.w};
#pragma unroll
            for (int i = 0; i < 4; i++)
#pragma unroll
                for (int j = 0; j < 4; j++)
                    acc[i][j] += a[i] * b[j];
        }
    }

    {
        const int n = bn + tx * 4;
        float4 bv = *(const float4*)&bias[n];
#pragma unroll
        for (int i = 0; i < 4; i++) {
            const int m = bm + ty * 4 + i;
            float4 cv;
            cv.x = acc[i][0] + bv.x;
            cv.y = acc[i][1] + bv.y;
            cv.z = acc[i][2] + bv.z;
            cv.w = acc[i][3] + bv.w;
            *(float4*)&C[(size_t)m * N + n] = cv;
        }
    }
}

// ---------------------------------------------------------------------------
// R15 fused kernel: byte-identical to R14 (the validated best).
//   blocks 0..127   : scan (R10 core, plain cached outs stores)
//   blocks 128..255 : phase-1 xp GEMM workers, then EXIT (return).
// Iron rule (R2/R12/R13, 4 confirmations): during the live exchange every
// other CU must be DEAD -- not sleeping, not polling, dead.
// ---------------------------------------------------------------------------
__global__ __launch_bounds__(1024) void rnn_fused(
    const float* __restrict__ x,     // (T,H) input
    const float* __restrict__ Wih,   // (H,H)
    const float* __restrict__ bih,   // (H)
    const float* __restrict__ Whh,   // (H,H)
    const float* __restrict__ bhh,   // (H)
    const float* __restrict__ h0,    // (H)
    float* __restrict__ xp,          // (T,H) ws: input projection
    float* __restrict__ outs,        // (T,H) ws: hidden states
    unsigned long long* __restrict__ mbox,  // [2][MBW] tagged fp16x2 mailbox
    int* __restrict__ chunk_done)    // [NCHUNK] xp-chunk arm counters
{
    const int tid = threadIdx.x;     // 0..1023

    if (blockIdx.x >= NB) {
        // ------------------- xp GEMM worker (exact R10) -------------------
        __shared__ float As[16][65];     // [kk][t-row], padded
        __shared__ float Bs[16][132];    // [kk][h-col], padded+aligned

        const int w2   = blockIdx.x - NB;   // 0..127
        const int ty   = tid >> 5;          // 0..31 -> t-rows ty*2, ty*2+1
        const int tx   = tid & 31;          // 0..31 -> h-cols tx*4..
        const int arow = tid >> 4;          // 0..63
        const int akk  = tid & 15;
        const int bcol = tid >> 3;          // 0..127
        const int bkk  = (tid & 7) * 2;

        for (int round = 0; round < (NCHUNK * NHT) / 128; ++round) {
            const int tile  = w2 + 128 * round;   // t-major: early t first
            const int chunk = tile >> 4;
            const int htile = tile & 15;
            const int bm = chunk * CHUNK_T;
            const int bn = htile * HTILE;

            float acc[2][4];
#pragma unroll
            for (int i = 0; i < 2; ++i)
#pragma unroll
                for (int j = 0; j < 4; ++j) acc[i][j] = 0.f;

            for (int k0 = 0; k0 < HH; k0 += 16) {
                float  av = x[(size_t)(bm + arow) * HH + k0 + akk];
                float2 bv = *(const float2*)&Wih[(size_t)(bn + bcol) * HH + k0 + bkk];
                __syncthreads();
                As[akk][arow]     = av;
                Bs[bkk][bcol]     = bv.x;
                Bs[bkk + 1][bcol] = bv.y;
                __syncthreads();
#pragma unroll
                for (int kk = 0; kk < 16; ++kk) {
                    float a0 = As[kk][ty * 2];
                    float a1 = As[kk][ty * 2 + 1];
                    float b0 = Bs[kk][tx * 4 + 0];
                    float b1 = Bs[kk][tx * 4 + 1];
                    float b2 = Bs[kk][tx * 4 + 2];
                    float b3 = Bs[kk][tx * 4 + 3];
                    acc[0][0] += a0 * b0; acc[0][1] += a0 * b1;
                    acc[0][2] += a0 * b2; acc[0][3] += a0 * b3;
                    acc[1][0] += a1 * b0; acc[1][1] += a1 * b1;
                    acc[1][2] += a1 * b2; acc[1][3] += a1 * b3;
                }
            }
#pragma unroll
            for (int i = 0; i < 2; ++i) {
                const int m = bm + ty * 2 + i;
#pragma unroll
                for (int j = 0; j < 4; ++j) {
                    const int n = bn + tx * 4 + j;
                    __hip_atomic_store(&xp[(size_t)m * HH + n],
                                       acc[i][j] + bih[n],
                                       __ATOMIC_RELAXED, __HIP_MEMORY_SCOPE_AGENT);
                }
            }
            __syncthreads();   // all waves' stores retired first
            if (tid == 0)
                __hip_atomic_fetch_add(&chunk_done[chunk], 1,
                                       __ATOMIC_RELEASE, __HIP_MEMORY_SCOPE_AGENT);
        }
        return;   // workers DIE here -- CUs go fully idle for the scan
    }

    // ------------------------- scan (exact R10 core) -----------------------
    const int b    = blockIdx.x;     // 0..127
    const int wave = tid >> 6;       // 0..15
    const int lane = tid & 63;
    const int r    = lane & 15;      // local row 0..15
    const int q    = lane >> 4;      // 0..3: interleaved 4-float subchunk
    const int row  = b * RPB + r;    // global row this thread accumulates
    const int m0   = wave * 64 + lane;      // my mailbox word (covers 2 rows)
    const int s0   = wave * 128 + 2 * lane; // my 2 floats in hs

    // weights pinned (atomic loads can't be rematerialized into the loop)
    float w[32];
#pragma unroll
    for (int jj = 0; jj < 8; ++jj)
#pragma unroll
        for (int i = 0; i < 4; ++i)
            w[jj * 4 + i] = __hip_atomic_load(
                &Whh[(size_t)row * HH + wave * 128 + jj * 16 + q * 4 + i],
                __ATOMIC_RELAXED, __HIP_MEMORY_SCOPE_WORKGROUP);

    const bool is_writer = (wave == 0) && (lane < RPB);
    const float bias = is_writer ? bhh[b * RPB + lane] : 0.f;

    __shared__ float hs[HH];               // staged h (fp32), wave-private
    __shared__ float partial[16][68];      // [k-chunk wave][q*17 + r]

    int last_c = -1;

    for (int t = 0; t < TT; ++t) {
        // xp gating + load: only writer lanes; poll only at chunk boundary
        float xpv = 0.f;
        if (is_writer) {
            const int c = t >> 6;   // t / CHUNK_T
            if (c != last_c) {
                while (__hip_atomic_load(&chunk_done[c],
                        __ATOMIC_RELAXED, __HIP_MEMORY_SCOPE_AGENT) < NHT) {}
                last_c = c;
            }
            xpv = __hip_atomic_load(&xp[(size_t)t * HH + b * RPB + lane],
                                    __ATOMIC_RELAXED, __HIP_MEMORY_SCOPE_AGENT);
        }

        // stage MY wave's 128-float chunk: ONE tagged word per lane
        if (t == 0) {
            float2 hv; hv.x = h0[s0]; hv.y = h0[s0 + 1];
            *(float2*)&hs[s0] = hv;
        } else {
            const unsigned int want = (unsigned int)t;
            const unsigned long long* mb = mbox + (size_t)(t & 1) * MBW;
            unsigned long long v;
            do {
                v = __hip_atomic_load(&mb[m0],
                    __ATOMIC_RELAXED, __HIP_MEMORY_SCOPE_AGENT);
            } while ((unsigned int)(v >> 32) != want);
            half2v hp = __builtin_bit_cast(half2v, (unsigned int)v);
            float2 hv;
            hv.x = (float)hp[0];
            hv.y = (float)hp[1];
            *(float2*)&hs[s0] = hv;   // same-wave write->read: lgkmcnt only
        }

        // matvec partial: 8 broadcast ds_read_b128 + 32 FMA (interleaved map)
        const float* hk = &hs[wave * 128 + q * 4];
        float p = 0.f;
#pragma unroll
        for (int jj = 0; jj < 8; ++jj) {
            float4 h4 = *(const float4*)&hk[jj * 16];
            p += w[jj * 4 + 0] * h4.x + w[jj * 4 + 1] * h4.y
               + w[jj * 4 + 2] * h4.z + w[jj * 4 + 3] * h4.w;
        }
        partial[wave][q * 17 + r] = p;
        __syncthreads();   // (B) the ONLY barrier per step

        if (wave == 0) {
            // lane l: row = l&15, qq = l>>4; sum over the 16 k-chunk waves
            const int idx = (lane >> 4) * 17 + (lane & 15);
            float s = 0.f;
#pragma unroll
            for (int g = 0; g < 16; ++g) s += partial[g][idx];
            s += __shfl_xor(s, 16, 64);   // fold qq bit 0
            s += __shfl_xor(s, 32, 64);   // fold qq bit 1
            float z = xpv + bias + s;
            z = fminf(15.f, fmaxf(-15.f, z));
            float e = __builtin_exp2f(z * 2.885390082f);
            float hv = (e - 1.f) * __builtin_amdgcn_rcpf(e + 1.f);
            // pack rows 2i,2i+1 into lane i (i<8): one 64B-line publish FIRST
            float ha = __shfl(hv, 2 * lane, 64);
            float hb = __shfl(hv, 2 * lane + 1, 64);
            if (lane < 8) {
                half2v pk2 = __builtin_amdgcn_cvt_pkrtz(ha, hb);
                unsigned int pb = __builtin_bit_cast(unsigned int, pk2);
                unsigned long long word =
                    ((unsigned long long)(unsigned int)(t + 1) << 32) |
                    (unsigned long long)pb;
                __hip_atomic_store(&mbox[(size_t)((t + 1) & 1) * MBW + b * 8 + lane],
                                   word, __ATOMIC_RELAXED, __HIP_MEMORY_SCOPE_AGENT);
            }
            if (lane < RPB)
                outs[(size_t)t * HH + b * RPB + lane] = hv;  // plain cached
        }
        // partial[w] overwrite for t+1 gated by wave w's next poll, which
        // requires this block's wave-0 publish (after the reads above).
    }
}

// ---------------------------------------------------------------------------
extern "C" void kernel_launch(void* const* d_in, const int* in_sizes, int n_in,
                              void* d_out, int out_size, void* d_ws, size_t ws_size,
                              hipStream_t stream)
{
    const float* x     = (const float*)d_in[0];  // (T,1,H)
    const float* W_ih  = (const float*)d_in[1];  // (H,H)
    const float* W_hh  = (const float*)d_in[2];  // (H,H)
    const float* b_ih  = (const float*)d_in[3];  // (H)
    const float* b_hh  = (const float*)d_in[4];  // (H)
    const float* W_lin = (const float*)d_in[5];  // (O,H)
    const float* b_lin = (const float*)d_in[6];  // (O)
    const float* h0    = (const float*)d_in[7];  // (1,1,H)
    float* out = (float*)d_out;                  // (T,1,O)

    char* ws = (char*)d_ws;
    float* xp    = (float*)ws;                                       // 32 MB
    float* outs  = (float*)(ws + (size_t)TT * HH * 4);               // 32 MB
    unsigned long long* mbox =
        (unsigned long long*)(ws + 2 * (size_t)TT * HH * 4);         // 16 KB
    int* chunk_done =
        (int*)(ws + 2 * (size_t)TT * HH * 4 + 2 * MBW * 8);          // 256 B

    // chunk counters must start at 0 (ws arrives poisoned); mailbox needs
    // no init (t==0 reads h0; poisoned tag never equals a wanted tag).
    hipMemsetAsync(chunk_done, 0, NCHUNK * sizeof(int), stream);

    // Fused phase 1 + phase 2: scan blocks 0..127, xp workers 128..255
    rnn_fused<<<2 * NB, 1024, 0, stream>>>(
        x, W_ih, b_ih, W_hh, b_hh, h0, xp, outs, mbox, chunk_done);

    // Phase 3: out = outs @ W_lin^T + b_lin (512 blocks, 2/CU)
    gemm_nt_bias64<<<dim3(TT / 64, OO / 64), 256, 0, stream>>>(
        outs, W_lin, b_lin, out, TT, OO, HH);
}